// Round 1
// baseline (1836.785 us; speedup 1.0000x reference)
//
#include <hip/hip_runtime.h>
#include <math.h>

#define NB   8
#define NSEQ 4096
#define DIM  1024
#define NH   16
#define DH   64
#define M_TOT (NB*NSEQ)   // 32768

// ---------------------------------------------------------------------------
// GEMM1: Y[m][j] = sum_k X[m][k] * Wq[j][k]   (x @ W_qkv.T)
// plus column-square-sum accumulation: cn2[b][j] += sum_{rows in tile} Y^2
// BM=BN=128, BK=16, 256 threads, 8x8 micro-tile.
// ---------------------------------------------------------------------------
__global__ __launch_bounds__(256) void k_gemm1(
    const float* __restrict__ X, const float* __restrict__ Wq,
    float* __restrict__ Y, float* __restrict__ cn2)
{
  __shared__ float as[16][132];
  __shared__ float bs[16][132];
  const int tid = threadIdx.x;
  const int tx = tid & 15, ty = tid >> 4;
  const int m0 = blockIdx.x * 128;
  const int j0 = blockIdx.y * 128;
  const int lr = tid >> 2;          // 0..63
  const int lc = (tid & 3) * 4;     // 0,4,8,12

  float acc[8][8];
  #pragma unroll
  for (int i = 0; i < 8; ++i)
    #pragma unroll
    for (int j = 0; j < 8; ++j) acc[i][j] = 0.f;

  for (int k0 = 0; k0 < DIM; k0 += 16) {
    float4 a0 = *(const float4*)&X[(size_t)(m0+lr   )*DIM + k0 + lc];
    float4 a1 = *(const float4*)&X[(size_t)(m0+lr+64)*DIM + k0 + lc];
    float4 b0 = *(const float4*)&Wq[(size_t)(j0+lr   )*DIM + k0 + lc];
    float4 b1 = *(const float4*)&Wq[(size_t)(j0+lr+64)*DIM + k0 + lc];
    as[lc+0][lr]    = a0.x; as[lc+1][lr]    = a0.y; as[lc+2][lr]    = a0.z; as[lc+3][lr]    = a0.w;
    as[lc+0][lr+64] = a1.x; as[lc+1][lr+64] = a1.y; as[lc+2][lr+64] = a1.z; as[lc+3][lr+64] = a1.w;
    bs[lc+0][lr]    = b0.x; bs[lc+1][lr]    = b0.y; bs[lc+2][lr]    = b0.z; bs[lc+3][lr]    = b0.w;
    bs[lc+0][lr+64] = b1.x; bs[lc+1][lr+64] = b1.y; bs[lc+2][lr+64] = b1.z; bs[lc+3][lr+64] = b1.w;
    __syncthreads();
    #pragma unroll
    for (int kk = 0; kk < 16; ++kk) {
      float4 A0 = *(const float4*)&as[kk][ty*8];
      float4 A1 = *(const float4*)&as[kk][ty*8+4];
      float4 B0 = *(const float4*)&bs[kk][tx*8];
      float4 B1 = *(const float4*)&bs[kk][tx*8+4];
      float av[8] = {A0.x,A0.y,A0.z,A0.w,A1.x,A1.y,A1.z,A1.w};
      float bv[8] = {B0.x,B0.y,B0.z,B0.w,B1.x,B1.y,B1.z,B1.w};
      #pragma unroll
      for (int i = 0; i < 8; ++i)
        #pragma unroll
        for (int j = 0; j < 8; ++j)
          acc[i][j] = fmaf(av[i], bv[j], acc[i][j]);
    }
    __syncthreads();
  }

  // write Y
  #pragma unroll
  for (int i = 0; i < 8; ++i) {
    const size_t m = (size_t)(m0 + ty*8 + i);
    float4 o0 = {acc[i][0],acc[i][1],acc[i][2],acc[i][3]};
    float4 o1 = {acc[i][4],acc[i][5],acc[i][6],acc[i][7]};
    *(float4*)&Y[m*DIM + j0 + tx*8    ] = o0;
    *(float4*)&Y[m*DIM + j0 + tx*8 + 4] = o1;
  }

  // column sums of squares (reuse `as` LDS; safe: all past the last sync)
  #pragma unroll
  for (int j = 0; j < 8; ++j) {
    float s = 0.f;
    #pragma unroll
    for (int i = 0; i < 8; ++i) s = fmaf(acc[i][j], acc[i][j], s);
    as[ty][tx*8 + j] = s;
  }
  __syncthreads();
  if (tid < 128) {
    float s = 0.f;
    #pragma unroll
    for (int r = 0; r < 16; ++r) s += as[r][tid];
    const int b = m0 >> 12;   // 4096 rows per batch, tiles never straddle
    atomicAdd(&cn2[b*DIM + j0 + tid], s);
  }
}

// invcn2 = 1 / max(sqrt(cn2), 1e-12)^2
__global__ void k_fin1(const float* __restrict__ cn2, float* __restrict__ invcn2)
{
  int i = blockIdx.x*256 + threadIdx.x;
  float n = fmaxf(sqrtf(cn2[i]), 1e-12f);
  invcn2[i] = 1.0f / (n*n);
}

// ---------------------------------------------------------------------------
// logits -> softmax over heads -> Pi, plus Spi[b][h] = sum_n Pi
// one wave per row (b,n); 4 lanes per head.
// ---------------------------------------------------------------------------
__global__ __launch_bounds__(1024) void k_softmax(
    const float* __restrict__ Y, const float* __restrict__ invcn2,
    const float* __restrict__ temp, float* __restrict__ Pi, float* __restrict__ Spi)
{
  __shared__ float sp[NH];
  const int tid = threadIdx.x;
  if (tid < NH) sp[tid] = 0.f;
  __syncthreads();

  const int wid = tid >> 6, lane = tid & 63;
  const size_t m = (size_t)blockIdx.x * 16 + wid;
  const int b = (int)(m >> 12);
  const float* yr = &Y[m*DIM];
  const float* iv = &invcn2[(size_t)b*DIM];

  float l = 0.f;
  const int c0 = lane * 16;
  #pragma unroll
  for (int q = 0; q < 4; ++q) {
    float4 y = *(const float4*)&yr[c0 + q*4];
    float4 v = *(const float4*)&iv[c0 + q*4];
    l += y.x*y.x*v.x + y.y*y.y*v.y + y.z*y.z*v.z + y.w*y.w*v.w;
  }
  // reduce within 4-lane head group
  l += __shfl_xor(l, 1);
  l += __shfl_xor(l, 2);
  const int h = lane >> 2;
  l *= temp[h];
  // max over the 16 heads (group-id bits 2..5)
  float mx = l;
  #pragma unroll
  for (int d = 4; d <= 32; d <<= 1) mx = fmaxf(mx, __shfl_xor(mx, d));
  float e = expf(l - mx);
  float s = e;
  #pragma unroll
  for (int d = 4; d <= 32; d <<= 1) s += __shfl_xor(s, d);
  float pi = e / s;
  if ((lane & 3) == 0) {
    Pi[m*NH + h] = pi;
    atomicAdd(&sp[h], pi);
  }
  __syncthreads();
  if (tid < NH) atomicAdd(&Spi[b*NH + tid], sp[tid]);
}

// ---------------------------------------------------------------------------
// dots[b][c] += sum_rows Pi[m][h(c)] * Y[m][c]^2   (16 rows per block)
// ---------------------------------------------------------------------------
__global__ __launch_bounds__(256) void k_dots(
    const float* __restrict__ Y, const float* __restrict__ Pi,
    float* __restrict__ dots)
{
  const int tid = threadIdx.x;
  const size_t m0 = (size_t)blockIdx.x * 16;
  const int b = (int)(m0 >> 12);
  const int c = tid * 4;
  const int h = c >> 6;
  float4 acc = {0.f,0.f,0.f,0.f};
  for (int r = 0; r < 16; ++r) {
    const size_t m = m0 + r;
    float4 y = *(const float4*)&Y[m*DIM + c];
    float pi = Pi[m*NH + h];
    acc.x = fmaf(pi*y.x, y.x, acc.x);
    acc.y = fmaf(pi*y.y, y.y, acc.y);
    acc.z = fmaf(pi*y.z, y.z, acc.z);
    acc.w = fmaf(pi*y.w, y.w, acc.w);
  }
  atomicAdd(&dots[b*DIM + c    ], acc.x);
  atomicAdd(&dots[b*DIM + c + 1], acc.y);
  atomicAdd(&dots[b*DIM + c + 2], acc.z);
  atomicAdd(&dots[b*DIM + c + 3], acc.w);
}

// attn = 1 / (1 + dots / (Spi + 1e-8))
__global__ void k_fin2(const float* __restrict__ dots, const float* __restrict__ Spi,
                       float* __restrict__ attn)
{
  int i = blockIdx.x*256 + threadIdx.x;   // i = b*1024 + c
  int b = i >> 10;
  int h = (i >> 6) & 15;
  float pn = dots[i] / (Spi[b*NH + h] + 1e-8f);
  attn[i] = 1.0f / (1.0f + pn);
}

// ---------------------------------------------------------------------------
// GEMM2: Out[m][j] = sum_c (-Y[m][c]*Pi[m][h(c)]*attn[b][c]) * Wo[j][c] + bias[j]
// scaling fused into the A-tile staging.
// ---------------------------------------------------------------------------
__global__ __launch_bounds__(256) void k_gemm2(
    const float* __restrict__ Y, const float* __restrict__ Wo,
    const float* __restrict__ Pi, const float* __restrict__ attn,
    const float* __restrict__ bias, float* __restrict__ Out)
{
  __shared__ float as[16][132];
  __shared__ float bs[16][132];
  const int tid = threadIdx.x;
  const int tx = tid & 15, ty = tid >> 4;
  const int m0 = blockIdx.x * 128;
  const int j0 = blockIdx.y * 128;
  const int b  = m0 >> 12;
  const int lr = tid >> 2;
  const int lc = (tid & 3) * 4;

  float acc[8][8];
  #pragma unroll
  for (int i = 0; i < 8; ++i)
    #pragma unroll
    for (int j = 0; j < 8; ++j) acc[i][j] = 0.f;

  for (int k0 = 0; k0 < DIM; k0 += 16) {
    const int c = k0 + lc;
    const int h = c >> 6;
    float4 a0 = *(const float4*)&Y[(size_t)(m0+lr   )*DIM + c];
    float4 a1 = *(const float4*)&Y[(size_t)(m0+lr+64)*DIM + c];
    float4 at = *(const float4*)&attn[(size_t)b*DIM + c];
    float pi0 = -Pi[(size_t)(m0+lr   )*NH + h];
    float pi1 = -Pi[(size_t)(m0+lr+64)*NH + h];
    float4 b0 = *(const float4*)&Wo[(size_t)(j0+lr   )*DIM + c];
    float4 b1 = *(const float4*)&Wo[(size_t)(j0+lr+64)*DIM + c];
    as[lc+0][lr]    = a0.x*pi0*at.x; as[lc+1][lr]    = a0.y*pi0*at.y;
    as[lc+2][lr]    = a0.z*pi0*at.z; as[lc+3][lr]    = a0.w*pi0*at.w;
    as[lc+0][lr+64] = a1.x*pi1*at.x; as[lc+1][lr+64] = a1.y*pi1*at.y;
    as[lc+2][lr+64] = a1.z*pi1*at.z; as[lc+3][lr+64] = a1.w*pi1*at.w;
    bs[lc+0][lr]    = b0.x; bs[lc+1][lr]    = b0.y; bs[lc+2][lr]    = b0.z; bs[lc+3][lr]    = b0.w;
    bs[lc+0][lr+64] = b1.x; bs[lc+1][lr+64] = b1.y; bs[lc+2][lr+64] = b1.z; bs[lc+3][lr+64] = b1.w;
    __syncthreads();
    #pragma unroll
    for (int kk = 0; kk < 16; ++kk) {
      float4 A0 = *(const float4*)&as[kk][ty*8];
      float4 A1 = *(const float4*)&as[kk][ty*8+4];
      float4 B0 = *(const float4*)&bs[kk][tx*8];
      float4 B1 = *(const float4*)&bs[kk][tx*8+4];
      float av[8] = {A0.x,A0.y,A0.z,A0.w,A1.x,A1.y,A1.z,A1.w};
      float bv[8] = {B0.x,B0.y,B0.z,B0.w,B1.x,B1.y,B1.z,B1.w};
      #pragma unroll
      for (int i = 0; i < 8; ++i)
        #pragma unroll
        for (int j = 0; j < 8; ++j)
          acc[i][j] = fmaf(av[i], bv[j], acc[i][j]);
    }
    __syncthreads();
  }

  float4 bi0 = *(const float4*)&bias[j0 + tx*8    ];
  float4 bi1 = *(const float4*)&bias[j0 + tx*8 + 4];
  #pragma unroll
  for (int i = 0; i < 8; ++i) {
    const size_t m = (size_t)(m0 + ty*8 + i);
    float4 o0 = {acc[i][0]+bi0.x, acc[i][1]+bi0.y, acc[i][2]+bi0.z, acc[i][3]+bi0.w};
    float4 o1 = {acc[i][4]+bi1.x, acc[i][5]+bi1.y, acc[i][6]+bi1.z, acc[i][7]+bi1.w};
    *(float4*)&Out[m*DIM + j0 + tx*8    ] = o0;
    *(float4*)&Out[m*DIM + j0 + tx*8 + 4] = o1;
  }
}

// ---------------------------------------------------------------------------
extern "C" void kernel_launch(void* const* d_in, const int* in_sizes, int n_in,
                              void* d_out, int out_size, void* d_ws, size_t ws_size,
                              hipStream_t stream)
{
  const float* X    = (const float*)d_in[0];
  const float* Wq   = (const float*)d_in[1];
  const float* temp = (const float*)d_in[2];
  const float* Wo   = (const float*)d_in[3];
  const float* bias = (const float*)d_in[4];
  float* Out = (float*)d_out;

  float* Y      = (float*)d_ws;                        // M*D
  float* cn2    = Y      + (size_t)M_TOT*DIM;          // B*D
  float* invcn2 = cn2    + (size_t)NB*DIM;             // B*D
  float* Pi     = invcn2 + (size_t)NB*DIM;             // M*NH
  float* Spi    = Pi     + (size_t)M_TOT*NH;           // B*NH
  float* dots   = Spi    + (size_t)NB*NH;              // B*D
  float* attn   = dots   + (size_t)NB*DIM;             // B*D

  hipMemsetAsync(cn2, 0, sizeof(float)*(size_t)NB*DIM, stream);
  hipMemsetAsync(Spi, 0, sizeof(float)*((size_t)NB*NH + (size_t)NB*DIM), stream);

  dim3 g1(M_TOT/128, DIM/128);
  k_gemm1<<<g1, 256, 0, stream>>>(X, Wq, Y, cn2);
  k_fin1<<<(NB*DIM)/256, 256, 0, stream>>>(cn2, invcn2);
  k_softmax<<<M_TOT/16, 1024, 0, stream>>>(Y, invcn2, temp, Pi, Spi);
  k_dots<<<M_TOT/16, 256, 0, stream>>>(Y, Pi, dots);
  k_fin2<<<(NB*DIM)/256, 256, 0, stream>>>(dots, Spi, attn);
  k_gemm2<<<g1, 256, 0, stream>>>(Y, Wo, Pi, attn, bias, Out);
}

// Round 3
// 856.993 us; speedup vs baseline: 2.1433x; 2.1433x over previous
//
#include <hip/hip_runtime.h>
#include <math.h>

#define NB   8
#define NSEQ 4096
#define DIM  1024
#define NH   16
#define M_TOT (NB*NSEQ)   // 32768
#define BK   32
#define LDK  40           // padded row stride (ushorts): 20 words -> 2-way banks (free)

typedef __attribute__((ext_vector_type(8))) short bf16x8;
typedef __attribute__((ext_vector_type(8))) ushort u16x8;
typedef __attribute__((ext_vector_type(4))) float f32x4;

__device__ inline ushort f2bf(float x) {          // RNE fp32 -> bf16 bits
  unsigned u = __float_as_uint(x);
  u += 0x7fff + ((u >> 16) & 1);
  return (ushort)(u >> 16);
}
__device__ inline float bf2f(ushort h) {
  return __uint_as_float(((unsigned)h) << 16);
}

// split 16 consecutive fp32 into bf16 hi/lo halves; write as 2x16B per half
__device__ inline void split_store(const float* v, ushort* dsth, ushort* dstl) {
  u16x8 h0, h1, l0, l1;
  #pragma unroll
  for (int t = 0; t < 8; ++t) {
    ushort h = f2bf(v[t]);
    h0[t] = h;
    l0[t] = f2bf(v[t] - bf2f(h));
  }
  #pragma unroll
  for (int t = 0; t < 8; ++t) {
    ushort h = f2bf(v[8+t]);
    h1[t] = h;
    l1[t] = f2bf(v[8+t] - bf2f(h));
  }
  *(u16x8*)(dsth)     = h0;
  *(u16x8*)(dsth + 8) = h1;
  *(u16x8*)(dstl)     = l0;
  *(u16x8*)(dstl + 8) = l1;
}

// ---------------------------------------------------------------------------
// GEMM1: Y = X @ Wq^T  (fp32 in/out, bf16x3 MFMA core) + cn2 column sum-sq
// ---------------------------------------------------------------------------
__global__ __launch_bounds__(256) void k_gemm1(
    const float* __restrict__ X, const float* __restrict__ Wq,
    float* __restrict__ Y, float* __restrict__ cn2)
{
  __shared__ __align__(16) ushort Ah[128*LDK], Al[128*LDK], Bh[128*LDK], Bl[128*LDK];
  const int tid  = threadIdx.x;
  const int lane = tid & 63;
  const int wave = tid >> 6;
  const int wr = wave >> 1, wc = wave & 1;      // wave -> 64x64 quadrant
  const int lr  = tid >> 1;                     // staging row 0..127
  const int lcg = (tid & 1) * 16;               // staging col group
  const int m0 = blockIdx.y * 128;
  const int j0 = blockIdx.x * 128;
  const int frow = lane & 15;
  const int fk   = (lane >> 4) * 8;

  f32x4 acc[4][4] = {};

  for (int k0 = 0; k0 < DIM; k0 += BK) {
    float av[16], bv[16];
    const float* ap = &X [(size_t)(m0+lr)*DIM + k0 + lcg];
    const float* bp = &Wq[(size_t)(j0+lr)*DIM + k0 + lcg];
    #pragma unroll
    for (int q = 0; q < 4; ++q) {
      *(float4*)&av[q*4] = *(const float4*)&ap[q*4];
      *(float4*)&bv[q*4] = *(const float4*)&bp[q*4];
    }
    __syncthreads();   // protect LDS from previous iter's readers
    split_store(av, &Ah[lr*LDK + lcg], &Al[lr*LDK + lcg]);
    split_store(bv, &Bh[lr*LDK + lcg], &Bl[lr*LDK + lcg]);
    __syncthreads();

    bf16x8 fah[4], fal[4], fbh[4], fbl[4];
    #pragma unroll
    for (int i = 0; i < 4; ++i) {
      const int ar = wr*64 + i*16 + frow;
      const int br = wc*64 + i*16 + frow;
      fah[i] = *(const bf16x8*)&Ah[ar*LDK + fk];
      fal[i] = *(const bf16x8*)&Al[ar*LDK + fk];
      fbh[i] = *(const bf16x8*)&Bh[br*LDK + fk];
      fbl[i] = *(const bf16x8*)&Bl[br*LDK + fk];
    }
    #pragma unroll
    for (int i = 0; i < 4; ++i)
      #pragma unroll
      for (int j = 0; j < 4; ++j) {
        acc[i][j] = __builtin_amdgcn_mfma_f32_16x16x32_bf16(fah[i], fbh[j], acc[i][j], 0,0,0);
        acc[i][j] = __builtin_amdgcn_mfma_f32_16x16x32_bf16(fah[i], fbl[j], acc[i][j], 0,0,0);
        acc[i][j] = __builtin_amdgcn_mfma_f32_16x16x32_bf16(fal[i], fbh[j], acc[i][j], 0,0,0);
      }
  }

  // write Y (C/D layout: col = lane&15, row = (lane>>4)*4 + reg)
  #pragma unroll
  for (int i = 0; i < 4; ++i) {
    const int mrow = m0 + wr*64 + i*16 + (lane>>4)*4;
    #pragma unroll
    for (int j = 0; j < 4; ++j) {
      const int col = j0 + wc*64 + j*16 + (lane & 15);
      #pragma unroll
      for (int r = 0; r < 4; ++r)
        Y[(size_t)(mrow+r)*DIM + col] = acc[i][j][r];
    }
  }

  // column sum of squares -> cn2
  const int b = m0 >> 12;
  #pragma unroll
  for (int j = 0; j < 4; ++j) {
    float s = 0.f;
    #pragma unroll
    for (int i = 0; i < 4; ++i)
      #pragma unroll
      for (int r = 0; r < 4; ++r) s = fmaf(acc[i][j][r], acc[i][j][r], s);
    s += __shfl_xor(s, 16);
    s += __shfl_xor(s, 32);
    if (lane < 16) atomicAdd(&cn2[b*DIM + j0 + wc*64 + j*16 + lane], s);
  }
}

// invcn2 = 1 / max(sqrt(cn2), 1e-12)^2
__global__ void k_fin1(const float* __restrict__ cn2, float* __restrict__ invcn2)
{
  int i = blockIdx.x*256 + threadIdx.x;
  float n = fmaxf(sqrtf(cn2[i]), 1e-12f);
  invcn2[i] = 1.0f / (n*n);
}

// ---------------------------------------------------------------------------
// logits -> softmax over heads -> Pi, plus Spi[b][h] = sum_n Pi
// ---------------------------------------------------------------------------
__global__ __launch_bounds__(1024) void k_softmax(
    const float* __restrict__ Y, const float* __restrict__ invcn2,
    const float* __restrict__ temp, float* __restrict__ Pi, float* __restrict__ Spi)
{
  __shared__ float sp[NH];
  const int tid = threadIdx.x;
  if (tid < NH) sp[tid] = 0.f;
  __syncthreads();

  const int wid = tid >> 6, lane = tid & 63;
  const size_t m = (size_t)blockIdx.x * 16 + wid;
  const int b = (int)(m >> 12);
  const float* yr = &Y[m*DIM];
  const float* iv = &invcn2[(size_t)b*DIM];

  float l = 0.f;
  const int c0 = lane * 16;
  #pragma unroll
  for (int q = 0; q < 4; ++q) {
    float4 y = *(const float4*)&yr[c0 + q*4];
    float4 v = *(const float4*)&iv[c0 + q*4];
    l += y.x*y.x*v.x + y.y*y.y*v.y + y.z*y.z*v.z + y.w*y.w*v.w;
  }
  l += __shfl_xor(l, 1);
  l += __shfl_xor(l, 2);
  const int h = lane >> 2;
  l *= temp[h];
  float mx = l;
  #pragma unroll
  for (int d = 4; d <= 32; d <<= 1) mx = fmaxf(mx, __shfl_xor(mx, d));
  float e = expf(l - mx);
  float s = e;
  #pragma unroll
  for (int d = 4; d <= 32; d <<= 1) s += __shfl_xor(s, d);
  float pi = e / s;
  if ((lane & 3) == 0) {
    Pi[m*NH + h] = pi;
    atomicAdd(&sp[h], pi);
  }
  __syncthreads();
  if (tid < NH) atomicAdd(&Spi[b*NH + tid], sp[tid]);
}

// ---------------------------------------------------------------------------
// dots[b][c] += sum_rows Pi[m][h(c)] * Y[m][c]^2
// ---------------------------------------------------------------------------
__global__ __launch_bounds__(256) void k_dots(
    const float* __restrict__ Y, const float* __restrict__ Pi,
    float* __restrict__ dots)
{
  const int tid = threadIdx.x;
  const size_t m0 = (size_t)blockIdx.x * 16;
  const int b = (int)(m0 >> 12);
  const int c = tid * 4;
  const int h = c >> 6;
  float4 acc = {0.f,0.f,0.f,0.f};
  for (int r = 0; r < 16; ++r) {
    const size_t m = m0 + r;
    float4 y = *(const float4*)&Y[m*DIM + c];
    float pi = Pi[m*NH + h];
    acc.x = fmaf(pi*y.x, y.x, acc.x);
    acc.y = fmaf(pi*y.y, y.y, acc.y);
    acc.z = fmaf(pi*y.z, y.z, acc.z);
    acc.w = fmaf(pi*y.w, y.w, acc.w);
  }
  atomicAdd(&dots[b*DIM + c    ], acc.x);
  atomicAdd(&dots[b*DIM + c + 1], acc.y);
  atomicAdd(&dots[b*DIM + c + 2], acc.z);
  atomicAdd(&dots[b*DIM + c + 3], acc.w);
}

// attn = 1 / (1 + dots / (Spi + 1e-8))
__global__ void k_fin2(const float* __restrict__ dots, const float* __restrict__ Spi,
                       float* __restrict__ attn)
{
  int i = blockIdx.x*256 + threadIdx.x;   // i = b*1024 + c
  int b = i >> 10;
  int h = (i >> 6) & 15;
  float pn = dots[i] / (Spi[b*NH + h] + 1e-8f);
  attn[i] = 1.0f / (1.0f + pn);
}

// ---------------------------------------------------------------------------
// GEMM2: Out = (-Y*Pi*attn) @ Wo^T + bias   (bf16x3 MFMA core)
// ---------------------------------------------------------------------------
__global__ __launch_bounds__(256) void k_gemm2(
    const float* __restrict__ Y, const float* __restrict__ Wo,
    const float* __restrict__ Pi, const float* __restrict__ attn,
    const float* __restrict__ bias, float* __restrict__ Out)
{
  __shared__ __align__(16) ushort Ah[128*LDK], Al[128*LDK], Bh[128*LDK], Bl[128*LDK];
  const int tid  = threadIdx.x;
  const int lane = tid & 63;
  const int wave = tid >> 6;
  const int wr = wave >> 1, wc = wave & 1;
  const int lr  = tid >> 1;
  const int lcg = (tid & 1) * 16;
  const int m0 = blockIdx.y * 128;
  const int j0 = blockIdx.x * 128;
  const int b  = m0 >> 12;
  const int frow = lane & 15;
  const int fk   = (lane >> 4) * 8;

  f32x4 acc[4][4] = {};

  for (int k0 = 0; k0 < DIM; k0 += BK) {
    const int c0 = k0 + lcg;                 // 16 cols stay within one head (c0%64 in {0,16,32,48})
    const int h  = c0 >> 6;
    float av[16], bv[16];
    const float* ap = &Y [(size_t)(m0+lr)*DIM + c0];
    const float* bp = &Wo[(size_t)(j0+lr)*DIM + k0 + lcg];
    const float* tp = &attn[(size_t)b*DIM + c0];
    const float pi = -Pi[(size_t)(m0+lr)*NH + h];
    #pragma unroll
    for (int q = 0; q < 4; ++q) {
      float4 a = *(const float4*)&ap[q*4];
      float4 t = *(const float4*)&tp[q*4];
      av[q*4+0] = a.x*pi*t.x; av[q*4+1] = a.y*pi*t.y;
      av[q*4+2] = a.z*pi*t.z; av[q*4+3] = a.w*pi*t.w;
      *(float4*)&bv[q*4] = *(const float4*)&bp[q*4];
    }
    __syncthreads();
    split_store(av, &Ah[lr*LDK + lcg], &Al[lr*LDK + lcg]);
    split_store(bv, &Bh[lr*LDK + lcg], &Bl[lr*LDK + lcg]);
    __syncthreads();

    bf16x8 fah[4], fal[4], fbh[4], fbl[4];
    #pragma unroll
    for (int i = 0; i < 4; ++i) {
      const int ar = wr*64 + i*16 + frow;
      const int br = wc*64 + i*16 + frow;
      fah[i] = *(const bf16x8*)&Ah[ar*LDK + fk];
      fal[i] = *(const bf16x8*)&Al[ar*LDK + fk];
      fbh[i] = *(const bf16x8*)&Bh[br*LDK + fk];
      fbl[i] = *(const bf16x8*)&Bl[br*LDK + fk];
    }
    #pragma unroll
    for (int i = 0; i < 4; ++i)
      #pragma unroll
      for (int j = 0; j < 4; ++j) {
        acc[i][j] = __builtin_amdgcn_mfma_f32_16x16x32_bf16(fah[i], fbh[j], acc[i][j], 0,0,0);
        acc[i][j] = __builtin_amdgcn_mfma_f32_16x16x32_bf16(fah[i], fbl[j], acc[i][j], 0,0,0);
        acc[i][j] = __builtin_amdgcn_mfma_f32_16x16x32_bf16(fal[i], fbh[j], acc[i][j], 0,0,0);
      }
  }

  #pragma unroll
  for (int i = 0; i < 4; ++i) {
    const int mrow = m0 + wr*64 + i*16 + (lane>>4)*4;
    #pragma unroll
    for (int j = 0; j < 4; ++j) {
      const int col = j0 + wc*64 + j*16 + (lane & 15);
      const float bj = bias[col];
      #pragma unroll
      for (int r = 0; r < 4; ++r)
        Out[(size_t)(mrow+r)*DIM + col] = acc[i][j][r] + bj;
    }
  }
}

// ---------------------------------------------------------------------------
extern "C" void kernel_launch(void* const* d_in, const int* in_sizes, int n_in,
                              void* d_out, int out_size, void* d_ws, size_t ws_size,
                              hipStream_t stream)
{
  const float* X    = (const float*)d_in[0];
  const float* Wq   = (const float*)d_in[1];
  const float* temp = (const float*)d_in[2];
  const float* Wo   = (const float*)d_in[3];
  const float* bias = (const float*)d_in[4];
  float* Out = (float*)d_out;

  float* Y      = (float*)d_ws;                        // M*D
  float* cn2    = Y      + (size_t)M_TOT*DIM;          // B*D
  float* invcn2 = cn2    + (size_t)NB*DIM;             // B*D
  float* Pi     = invcn2 + (size_t)NB*DIM;             // M*NH
  float* Spi    = Pi     + (size_t)M_TOT*NH;           // B*NH
  float* dots   = Spi    + (size_t)NB*NH;              // B*D
  float* attn   = dots   + (size_t)NB*DIM;             // B*D

  hipMemsetAsync(cn2, 0, sizeof(float)*(size_t)NB*DIM, stream);
  hipMemsetAsync(Spi, 0, sizeof(float)*((size_t)NB*NH + (size_t)NB*DIM), stream);

  dim3 g1(DIM/128, M_TOT/128);   // x = j-block (8), y = m-block (256)
  k_gemm1<<<g1, 256, 0, stream>>>(X, Wq, Y, cn2);
  k_fin1<<<(NB*DIM)/256, 256, 0, stream>>>(cn2, invcn2);
  k_softmax<<<M_TOT/16, 1024, 0, stream>>>(Y, invcn2, temp, Pi, Spi);
  k_dots<<<M_TOT/16, 256, 0, stream>>>(Y, Pi, dots);
  k_fin2<<<(NB*DIM)/256, 256, 0, stream>>>(dots, Spi, attn);
  k_gemm2<<<g1, 256, 0, stream>>>(Y, Wo, Pi, attn, bias, Out);
}

// Round 5
// 684.873 us; speedup vs baseline: 2.6819x; 1.2513x over previous
//
#include <hip/hip_runtime.h>
#include <math.h>

#define NB   8
#define NSEQ 4096
#define DIM  1024
#define NH   16
#define M_TOT (NB*NSEQ)   // 32768

typedef __attribute__((ext_vector_type(8))) short bf16x8;
typedef __attribute__((ext_vector_type(8))) ushort u16x8;
typedef __attribute__((ext_vector_type(4))) float f32x4;

__device__ inline ushort f2bf(float x) {          // RNE fp32 -> bf16 bits
  unsigned u = __float_as_uint(x);
  u += 0x7fff + ((u >> 16) & 1);
  return (ushort)(u >> 16);
}
__device__ inline float bf2f(ushort h) {
  return __uint_as_float(((unsigned)h) << 16);
}

// async global->LDS, 16B per lane; dest = uniform lds base + lane*16
#define GLOAD16(gsrc, ldst) \
  __builtin_amdgcn_global_load_lds( \
      (const __attribute__((address_space(1))) void*)(gsrc), \
      (__attribute__((address_space(3))) void*)(ldst), 16, 0, 0)

// ---------------------------------------------------------------------------
// k_split: in-place hi/lo bf16 split of X, Wq, Wo.
// Each 32B group (8 fp32) -> 16B hi bf16x8 at +0, 16B lo bf16x8 at +16.
// Safe in-place: each thread reads/writes only its own 32B.
// ---------------------------------------------------------------------------
#define GX ((size_t)M_TOT*DIM/8)       // 4194304 groups
#define GW ((size_t)DIM*DIM/8)         // 131072 groups

__global__ __launch_bounds__(256) void k_split(
    float* __restrict__ X, float* __restrict__ Wq, float* __restrict__ Wo)
{
  size_t g = (size_t)blockIdx.x*256 + threadIdx.x;
  char* p;
  if (g < GX)            p = (char*)X  + g*32;
  else if (g < GX + GW)  p = (char*)Wq + (g - GX)*32;
  else                   p = (char*)Wo + (g - GX - GW)*32;
  float4 v0 = *(const float4*)p;
  float4 v1 = *(const float4*)(p + 16);
  float v[8] = {v0.x,v0.y,v0.z,v0.w,v1.x,v1.y,v1.z,v1.w};
  u16x8 hh, ll;
  #pragma unroll
  for (int t = 0; t < 8; ++t) {
    ushort hb = f2bf(v[t]);
    hh[t] = hb;
    ll[t] = f2bf(v[t] - bf2f(hb));
  }
  *(u16x8*)p        = hh;
  *(u16x8*)(p + 16) = ll;
}

// ---------------------------------------------------------------------------
// Unified bf16x3 GEMM: C = A @ B^T from pre-split hi/lo operands.
// A rows stride 4096B (128 groups of {16B hi,16B lo}); same for B.
// 128x128 tile, BK=32, 4 waves (64x64 each), global_load_lds staging,
// LDS content swizzled: LDS[row][slot] = G[row][slot ^ (row&3)] (16B slots).
// G2=false: C=Y + cn2 column sum-sq epilogue.  G2=true: C=Out + bias.
// ---------------------------------------------------------------------------
template<bool G2>
__global__ __launch_bounds__(256) void k_gemm(
    const char* __restrict__ Abase, const char* __restrict__ Bbase,
    float* __restrict__ Cout, float* __restrict__ cn2,
    const float* __restrict__ bias)
{
  __shared__ __align__(16) char Ah[8192], Al[8192], Bh[8192], Bl[8192];
  const int tid  = threadIdx.x;
  const int lane = tid & 63;
  const int w    = tid >> 6;
  const int wr = w >> 1, wc = w & 1;
  const int m0 = blockIdx.y * 128;
  const int j0 = blockIdx.x * 128;
  const int frow = lane & 15;
  const int grp  = lane >> 4;

  // staging sources: wave w stages chunks q=w*2+s (rows q*16+lane/4)
  const char* srcA[2][2];
  const char* srcB[2][2];
  int ldsOff[2];
  #pragma unroll
  for (int s = 0; s < 2; ++s) {
    const int q    = w*2 + s;
    const int row  = q*16 + (lane >> 2);
    const int slotX = (lane & 3) ^ (row & 3);      // inverse-swizzled source
    ldsOff[s] = q * 1024;
    #pragma unroll
    for (int hl = 0; hl < 2; ++hl) {
      srcA[s][hl] = Abase + (size_t)(m0+row)*4096 + slotX*32 + hl*16;
      srcB[s][hl] = Bbase + (size_t)(j0+row)*4096 + slotX*32 + hl*16;
    }
  }

  // fragment LDS byte offsets (constant over K): swizzled read
  int aOff[4], bOff[4];
  #pragma unroll
  for (int i = 0; i < 4; ++i) {
    const int ar = wr*64 + i*16 + frow;
    const int br = wc*64 + i*16 + frow;
    aOff[i] = ar*64 + ((grp ^ (ar & 3)) << 4);
    bOff[i] = br*64 + ((grp ^ (br & 3)) << 4);
  }

  f32x4 acc[4][4] = {};

  for (int k = 0; k < DIM/32; ++k) {
    __syncthreads();     // prev-iter readers done before overwrite
    #pragma unroll
    for (int s = 0; s < 2; ++s) {
      GLOAD16(srcA[s][0], Ah + ldsOff[s]);
      GLOAD16(srcA[s][1], Al + ldsOff[s]);
      GLOAD16(srcB[s][0], Bh + ldsOff[s]);
      GLOAD16(srcB[s][1], Bl + ldsOff[s]);
      srcA[s][0] += 128; srcA[s][1] += 128;
      srcB[s][0] += 128; srcB[s][1] += 128;
    }
    __syncthreads();     // compiler drains vmcnt before barrier

    bf16x8 fah[4], fal[4], fbh[4], fbl[4];
    #pragma unroll
    for (int i = 0; i < 4; ++i) {
      fah[i] = *(const bf16x8*)(Ah + aOff[i]);
      fal[i] = *(const bf16x8*)(Al + aOff[i]);
      fbh[i] = *(const bf16x8*)(Bh + bOff[i]);
      fbl[i] = *(const bf16x8*)(Bl + bOff[i]);
    }
    #pragma unroll
    for (int i = 0; i < 4; ++i)
      #pragma unroll
      for (int j = 0; j < 4; ++j) {
        acc[i][j] = __builtin_amdgcn_mfma_f32_16x16x32_bf16(fah[i], fbh[j], acc[i][j], 0,0,0);
        acc[i][j] = __builtin_amdgcn_mfma_f32_16x16x32_bf16(fah[i], fbl[j], acc[i][j], 0,0,0);
        acc[i][j] = __builtin_amdgcn_mfma_f32_16x16x32_bf16(fal[i], fbh[j], acc[i][j], 0,0,0);
      }
  }

  // C write (C/D layout: col = lane&15, row = (lane>>4)*4 + reg)
  #pragma unroll
  for (int i = 0; i < 4; ++i) {
    const int mrow = m0 + wr*64 + i*16 + (lane>>4)*4;
    #pragma unroll
    for (int j = 0; j < 4; ++j) {
      const int col = j0 + wc*64 + j*16 + (lane & 15);
      const float bj = G2 ? bias[col] : 0.f;
      #pragma unroll
      for (int r = 0; r < 4; ++r)
        Cout[(size_t)(mrow+r)*DIM + col] = acc[i][j][r] + bj;
    }
  }

  if (!G2) {  // column sum of squares -> cn2
    const int b = m0 >> 12;
    #pragma unroll
    for (int j = 0; j < 4; ++j) {
      float s = 0.f;
      #pragma unroll
      for (int i = 0; i < 4; ++i)
        #pragma unroll
        for (int r = 0; r < 4; ++r) s = fmaf(acc[i][j][r], acc[i][j][r], s);
      s += __shfl_xor(s, 16);
      s += __shfl_xor(s, 32);
      if (lane < 16) atomicAdd(&cn2[b*DIM + j0 + wc*64 + j*16 + lane], s);
    }
  }
}

// ---------------------------------------------------------------------------
// k_rowpass: fused invcn2 + head-softmax + dots accumulation + Spi.
// Block 256 thr (4 waves), each wave processes 16 rows sequentially,
// lane owns 16 fixed columns (c0 = lane*16) -> register dots accumulator.
// ---------------------------------------------------------------------------
__global__ __launch_bounds__(256) void k_rowpass(
    const float* __restrict__ Y, const float* __restrict__ cn2,
    const float* __restrict__ temp, float* __restrict__ Pi,
    float* __restrict__ Spi, float* __restrict__ dots)
{
  __shared__ float dred[4][1024];
  const int tid = threadIdx.x, lane = tid & 63, w = tid >> 6;
  const int mBase = blockIdx.x*64 + w*16;
  const int b = (blockIdx.x*64) >> 12;
  const int c0 = lane*16;
  const int h = lane >> 2;

  float iv[16];
  #pragma unroll
  for (int q = 0; q < 4; ++q) {
    float4 cv = *(const float4*)&cn2[b*DIM + c0 + q*4];
    iv[q*4+0] = 1.f/fmaxf(cv.x, 1e-24f);
    iv[q*4+1] = 1.f/fmaxf(cv.y, 1e-24f);
    iv[q*4+2] = 1.f/fmaxf(cv.z, 1e-24f);
    iv[q*4+3] = 1.f/fmaxf(cv.w, 1e-24f);
  }
  const float th = temp[h];

  float dacc[16] = {};
  float spacc = 0.f;
  for (int r = 0; r < 16; ++r) {
    const size_t m = (size_t)(mBase + r);
    float y[16];
    #pragma unroll
    for (int q = 0; q < 4; ++q)
      *(float4*)&y[q*4] = *(const float4*)&Y[m*DIM + c0 + q*4];
    float l = 0.f;
    #pragma unroll
    for (int t = 0; t < 16; ++t) l = fmaf(y[t]*y[t], iv[t], l);
    l += __shfl_xor(l, 1);
    l += __shfl_xor(l, 2);
    l *= th;
    float mx = l;
    #pragma unroll
    for (int d = 4; d <= 32; d <<= 1) mx = fmaxf(mx, __shfl_xor(mx, d));
    float e = expf(l - mx);
    float s = e;
    #pragma unroll
    for (int d = 4; d <= 32; d <<= 1) s += __shfl_xor(s, d);
    float pi = e / s;
    if ((lane & 3) == 0) { Pi[m*NH + h] = pi; spacc += pi; }
    #pragma unroll
    for (int t = 0; t < 16; ++t) dacc[t] = fmaf(pi*y[t], y[t], dacc[t]);
  }
  if ((lane & 3) == 0) atomicAdd(&Spi[b*NH + h], spacc);

  #pragma unroll
  for (int t = 0; t < 16; ++t) dred[w][c0 + t] = dacc[t];
  __syncthreads();
  float4 s4 = {0,0,0,0};
  #pragma unroll
  for (int ww = 0; ww < 4; ++ww) {
    float4 v = *(const float4*)&dred[ww][tid*4];
    s4.x += v.x; s4.y += v.y; s4.z += v.z; s4.w += v.w;
  }
  atomicAdd(&dots[b*DIM + tid*4 + 0], s4.x);
  atomicAdd(&dots[b*DIM + tid*4 + 1], s4.y);
  atomicAdd(&dots[b*DIM + tid*4 + 2], s4.z);
  atomicAdd(&dots[b*DIM + tid*4 + 3], s4.w);
}

// ---------------------------------------------------------------------------
// k_build_a2: A2 = split(-Y * Pi * attn), attn computed inline,
// written IN PLACE over Y (same 32B-group layout as k_split output).
// ---------------------------------------------------------------------------
__global__ __launch_bounds__(256) void k_build_a2(
    float* __restrict__ Y, const float* __restrict__ Pi,
    const float* __restrict__ Spi, const float* __restrict__ dots)
{
  const size_t g = (size_t)blockIdx.x*256 + threadIdx.x;  // 8-elem group
  const size_t m = g >> 7;
  const int c0 = (int)(g & 127) * 8;
  const int b = (int)(m >> 12);
  const int h = c0 >> 6;
  char* p = (char*)Y + g*32;
  float4 y0 = *(const float4*)p;
  float4 y1 = *(const float4*)(p + 16);
  float y[8] = {y0.x,y0.y,y0.z,y0.w,y1.x,y1.y,y1.z,y1.w};
  const float pi  = -Pi[m*NH + h];
  const float spv = Spi[b*NH + h] + 1e-8f;
  const float* dp = &dots[b*DIM + c0];
  u16x8 hh, ll;
  #pragma unroll
  for (int t = 0; t < 8; ++t) {
    float at = 1.f / (1.f + dp[t] / spv);
    float a  = y[t] * pi * at;
    ushort hb = f2bf(a);
    hh[t] = hb;
    ll[t] = f2bf(a - bf2f(hb));
  }
  *(u16x8*)p        = hh;
  *(u16x8*)(p + 16) = ll;
}

// ---------------------------------------------------------------------------
extern "C" void kernel_launch(void* const* d_in, const int* in_sizes, int n_in,
                              void* d_out, int out_size, void* d_ws, size_t ws_size,
                              hipStream_t stream)
{
  float* X    = (float*)d_in[0];   // mutated in place (harness restores)
  float* Wq   = (float*)d_in[1];
  const float* temp = (const float*)d_in[2];
  float* Wo   = (float*)d_in[3];
  const float* bias = (const float*)d_in[4];
  float* Out = (float*)d_out;

  float* Y    = (float*)d_ws;                     // M*D fp32, later A2 hi/lo in place
  float* Pi   = Y    + (size_t)M_TOT*DIM;         // M*NH
  float* cn2  = Pi   + (size_t)M_TOT*NH;          // NB*DIM
  float* Spi  = cn2  + (size_t)NB*DIM;            // NB*NH
  float* dots = Spi  + (size_t)NB*NH;             // NB*DIM

  // zero cn2 + Spi + dots (contiguous)
  hipMemsetAsync(cn2, 0, sizeof(float)*((size_t)NB*DIM + NB*NH + (size_t)NB*DIM), stream);

  const int splitBlocks = (int)((GX + 2*GW) / 256);
  k_split<<<splitBlocks, 256, 0, stream>>>(X, Wq, Wo);

  dim3 g1(DIM/128, M_TOT/128);   // x = j-tile (8), y = m-tile (256)
  k_gemm<false><<<g1, 256, 0, stream>>>((const char*)X, (const char*)Wq, Y, cn2, nullptr);

  k_rowpass<<<M_TOT/64, 256, 0, stream>>>(Y, cn2, temp, Pi, Spi, dots);

  k_build_a2<<<(int)(((size_t)M_TOT*DIM/8)/256), 256, 0, stream>>>(Y, Pi, Spi, dots);

  k_gemm<true><<<g1, 256, 0, stream>>>((const char*)Y, (const char*)Wo, Out, nullptr, bias);
}